// Round 4
// baseline (239.093 us; speedup 1.0000x reference)
//
#include <hip/hip_runtime.h>
#include <stdint.h>

// Self-attention, B=4, S=2048, D=1024, fp32 in/out, bf16 MFMA internally.
// R9: faithful m201-template port. Identical schedule/geometry to R6/R7 but
//     with the three poisons removed:
//       - NO asm memory-clobber fences (R6: each one made the waitcnt pass
//         insert a full vmcnt(0) drain -> synchronous loop, 27% MfmaUtil)
//       - NO sched_barrier(0) order-pinning (R7: m141 failure mode)
//       - plain C++ ds_reads, not volatile-asm reads (compiler manages lgkm)
//     Kept: raw s_barrier, one counted vmcnt(VMN) per K-tile (never 0 in
//     steady state), setprio(1) around MFMA clusters, BK=64 XOR swizzle.

typedef float f32x4 __attribute__((ext_vector_type(4)));
typedef short s16x8 __attribute__((ext_vector_type(8)));

__device__ __forceinline__ uint16_t f2bf(float f) {
    uint32_t u = __float_as_uint(f);
    u += 0x7fffu + ((u >> 16) & 1u);   // round-to-nearest-even
    return (uint16_t)(u >> 16);
}

#define GLOAD16(gp, lp)                                                  \
    __builtin_amdgcn_global_load_lds(                                    \
        (const __attribute__((address_space(1))) uint32_t*)(gp),         \
        (__attribute__((address_space(3))) uint32_t*)(lp), 16, 0, 0)

#define BAR() __builtin_amdgcn_s_barrier()
#define LGKM0() asm volatile("s_waitcnt lgkmcnt(0)")

template <int N> __device__ __forceinline__ void waitv() {
    if constexpr (N == 8)      asm volatile("s_waitcnt vmcnt(8)");
    else if constexpr (N == 6) asm volatile("s_waitcnt vmcnt(6)");
    else                       asm volatile("s_waitcnt vmcnt(0)");
}

// ---------------------------------------------------------------------------
// BK=64 swizzle (verified SQ_LDS_BANK_CONFLICT=0): LDS chunk cs (16B units)
// holds global kchunk (cs&7)^((cs>>3)&7) of row cs>>3. Fragment read for
// (row, kc): row*64 + (kc^(row&7))*8. C/D: row=(lane>>4)*4+reg, col=lane&15.
//
// Per K-tile t (slot s=t&1), 4 phase-pairs:
//   ph1: dsr A(M0)+B(N0)             | BAR | lgkm0 | MFMA M0N0 | BAR
//   ph2: dsr B(N1)                   | BAR | lgkm0 | MFMA M0N1 | BAR
//   ph3: dsr A(M1); glds B(t+2)->s   | BAR | lgkm0 | MFMA M1N1 | BAR
//   ph4:            glds A(t+2)->s   | BAR |         MFMA M1N0 | vmcnt(VMN) | BAR
// Restage safety: all ds_reads of a region drain at that phase's lgkm0 (per
// wave) which precedes the phase-end barrier, which precedes any glds into
// that region. Tile t+1's landing: at end of tile t, outstanding VMEM =
// t+1's VMN + t+2's issued loads; vmcnt(VMN) retires all of t+1, then the
// barrier extends that guarantee across all waves.
// ---------------------------------------------------------------------------
template <int MFRAG>
__device__ __forceinline__ void gemm8(
    uint16_t* lds,
    const uint16_t* __restrict__ Ag, const long long lda,
    const uint16_t* __restrict__ Bg, const long long ldb,
    const int NT, f32x4 (&acc)[MFRAG][4])
{
    constexpr int BM   = MFRAG * 32;          // 256 or 128
    constexpr int AGL  = BM / 64;             // A glds per thread (4 or 2)
    constexpr int MH   = MFRAG / 2;
    constexpr int SLOT = (BM + 256) * 64;     // uint16 units per dbuf slot
    constexpr int VMN  = AGL + 4;             // steady-state vmcnt (8 or 6)

    const int tid  = threadIdx.x;
    const int wave = tid >> 6, lane = tid & 63;
    const int lr   = lane & 15, hi = lane >> 4, lr7 = lane & 7;

    // staging addresses (512 threads cooperative; LDS dest wave-uniform)
    const uint16_t* gA[AGL]; int lA[AGL];
    const uint16_t* gB[4];   int lB[4];
#pragma unroll
    for (int p = 0; p < AGL; ++p) {
        const int cs = p * 512 + tid;
        const int rr = cs >> 3;
        const int kc = ((cs & 7) ^ (rr & 7)) * 8;
        gA[p] = Ag + (long long)rr * lda + kc;
        lA[p] = (p * 512 + wave * 64) * 8;
    }
#pragma unroll
    for (int p = 0; p < 4; ++p) {
        const int cs = p * 512 + tid;
        const int rr = cs >> 3;
        const int kc = ((cs & 7) ^ (rr & 7)) * 8;
        gB[p] = Bg + (long long)rr * ldb + kc;
        lB[p] = BM * 64 + (p * 512 + wave * 64) * 8;
    }

    // fragment-read bases
    const int wrow = (wave >> 2) * (MFRAG * 16);
    const int wcol = (wave & 3) * 64;
    const int arow = (wrow + lr) * 64;
    const int brow = BM * 64 + (wcol + lr) * 64;
    const int koff0 = (hi ^ lr7) * 8;
    const int koff1 = ((4 + hi) ^ lr7) * 8;

    // prologue: tile0 -> slot0, tile1 -> slot1; wait tile0 only
#pragma unroll
    for (int p = 0; p < AGL; ++p) GLOAD16(gA[p], lds + lA[p]);
#pragma unroll
    for (int p = 0; p < 4;  ++p) GLOAD16(gB[p], lds + lB[p]);
#pragma unroll
    for (int p = 0; p < AGL; ++p) GLOAD16(gA[p] + 64, lds + SLOT + lA[p]);
#pragma unroll
    for (int p = 0; p < 4;  ++p) GLOAD16(gB[p] + 64, lds + SLOT + lB[p]);
    waitv<VMN>();
    BAR();

    s16x8 a[MH][2], b0[2][2], b1[2][2];

    for (int t = 0; t < NT; ++t) {
        uint16_t* L = lds + (t & 1) * SLOT;
        const int k0 = (t + 2) * 64;
        const bool pf = (t + 2) < NT;

        // ---- phase 1: dsr A(M0) + B(N0); MFMA M0N0 ----
#pragma unroll
        for (int i = 0; i < MH; ++i) {
            a[i][0] = *(const s16x8*)(L + arow + i * 1024 + koff0);
            a[i][1] = *(const s16x8*)(L + arow + i * 1024 + koff1);
        }
#pragma unroll
        for (int j = 0; j < 2; ++j) {
            b0[j][0] = *(const s16x8*)(L + brow + j * 1024 + koff0);
            b0[j][1] = *(const s16x8*)(L + brow + j * 1024 + koff1);
        }
        BAR();
        LGKM0();
        __builtin_amdgcn_s_setprio(1);
#pragma unroll
        for (int kk = 0; kk < 2; ++kk)
#pragma unroll
            for (int i = 0; i < MH; ++i)
#pragma unroll
                for (int j = 0; j < 2; ++j)
                    acc[i][j] = __builtin_amdgcn_mfma_f32_16x16x32_bf16(
                        a[i][kk], b0[j][kk], acc[i][j], 0, 0, 0);
        __builtin_amdgcn_s_setprio(0);
        BAR();

        // ---- phase 2: dsr B(N1); MFMA M0N1 ----
#pragma unroll
        for (int j = 0; j < 2; ++j) {
            b1[j][0] = *(const s16x8*)(L + brow + (2 + j) * 1024 + koff0);
            b1[j][1] = *(const s16x8*)(L + brow + (2 + j) * 1024 + koff1);
        }
        BAR();
        LGKM0();
        __builtin_amdgcn_s_setprio(1);
#pragma unroll
        for (int kk = 0; kk < 2; ++kk)
#pragma unroll
            for (int i = 0; i < MH; ++i)
#pragma unroll
                for (int j = 0; j < 2; ++j)
                    acc[i][2 + j] = __builtin_amdgcn_mfma_f32_16x16x32_bf16(
                        a[i][kk], b1[j][kk], acc[i][2 + j], 0, 0, 0);
        __builtin_amdgcn_s_setprio(0);
        BAR();

        // ---- phase 3: dsr A(M1); glds B(t+2) into this slot ----
#pragma unroll
        for (int i = 0; i < MH; ++i) {
            a[i][0] = *(const s16x8*)(L + arow + (MH + i) * 1024 + koff0);
            a[i][1] = *(const s16x8*)(L + arow + (MH + i) * 1024 + koff1);
        }
        if (pf) {
#pragma unroll
            for (int p = 0; p < 4; ++p) GLOAD16(gB[p] + k0, L + lB[p]);
        }
        BAR();
        LGKM0();
        __builtin_amdgcn_s_setprio(1);
#pragma unroll
        for (int kk = 0; kk < 2; ++kk)
#pragma unroll
            for (int i = 0; i < MH; ++i)
#pragma unroll
                for (int j = 0; j < 2; ++j)
                    acc[MH + i][2 + j] = __builtin_amdgcn_mfma_f32_16x16x32_bf16(
                        a[i][kk], b1[j][kk], acc[MH + i][2 + j], 0, 0, 0);
        __builtin_amdgcn_s_setprio(0);
        BAR();

        // ---- phase 4: glds A(t+2); MFMA M1N0; counted vmcnt ----
        if (pf) {
#pragma unroll
            for (int p = 0; p < AGL; ++p) GLOAD16(gA[p] + k0, L + lA[p]);
        }
        BAR();
        __builtin_amdgcn_s_setprio(1);
#pragma unroll
        for (int kk = 0; kk < 2; ++kk)
#pragma unroll
            for (int i = 0; i < MH; ++i)
#pragma unroll
                for (int j = 0; j < 2; ++j)
                    acc[MH + i][j] = __builtin_amdgcn_mfma_f32_16x16x32_bf16(
                        a[i][kk], b0[j][kk], acc[MH + i][j], 0, 0, 0);
        __builtin_amdgcn_s_setprio(0);
        if (pf) waitv<VMN>(); else waitv<0>();
        BAR();
    }
}

// Q & K projection: C[8192][2048] = xb @ [Wq|Wk]^T. Grid (32,8): y<4 -> Q
// (scaled 2^-5 + bq), y>=4 -> K (+bk). 256 blocks.
__global__ __launch_bounds__(512, 2) void qk_proj8(
    const uint16_t* __restrict__ xb, const uint16_t* __restrict__ wqb,
    const uint16_t* __restrict__ wkb, const float* __restrict__ bq,
    const float* __restrict__ bk, uint16_t* __restrict__ qb,
    uint16_t* __restrict__ kb)
{
    __shared__ __attribute__((aligned(16))) uint16_t lds[2 * 512 * 64];
    const long long row0 = (long long)blockIdx.x * 256;
    const bool isQ = blockIdx.y < 4;
    const long long col0 = (long long)(blockIdx.y & 3) * 256;
    const uint16_t* W = isQ ? wqb : wkb;

    f32x4 acc[8][4] = {};
    gemm8<8>(lds, xb + row0 * 1024, 1024, W + col0 * 1024, 1024, 16, acc);

    const float* bias = isQ ? bq : bk;
    uint16_t* out = isQ ? qb : kb;
    const float scale = isQ ? 0.03125f : 1.0f;

    const int tid = threadIdx.x;
    const int wave = tid >> 6, lane = tid & 63;
    const int lr = lane & 15, hi = lane >> 4;
    const int wrow = (wave >> 2) * 128, wcol = (wave & 3) * 64;
#pragma unroll
    for (int i = 0; i < 8; ++i)
#pragma unroll
        for (int rr = 0; rr < 4; ++rr) {
            const long long row = row0 + wrow + i * 16 + hi * 4 + rr;
#pragma unroll
            for (int j = 0; j < 4; ++j) {
                const long long col = col0 + wcol + j * 16 + lr;
                out[row * 1024 + col] = f2bf((acc[i][j][rr] + bias[col]) * scale);
            }
        }
}

// V^T: Vt[1024][8192] = Wv @ xb^T + bv(row). Grid (8,32) = 256 blocks, BM=128.
__global__ __launch_bounds__(512, 2) void vt_proj8(
    const uint16_t* __restrict__ xb, const uint16_t* __restrict__ wvb,
    const float* __restrict__ bv, uint16_t* __restrict__ vtb)
{
    __shared__ __attribute__((aligned(16))) uint16_t lds[2 * 384 * 64];
    const long long row0 = (long long)blockIdx.x * 128;   // Wv / Vt row
    const long long col0 = (long long)blockIdx.y * 256;   // token col

    f32x4 acc[4][4] = {};
    gemm8<4>(lds, wvb + row0 * 1024, 1024, xb + col0 * 1024, 1024, 16, acc);

    const int tid = threadIdx.x;
    const int wave = tid >> 6, lane = tid & 63;
    const int lr = lane & 15, hi = lane >> 4;
    const int wrow = (wave >> 2) * 64, wcol = (wave & 3) * 64;
#pragma unroll
    for (int i = 0; i < 4; ++i)
#pragma unroll
        for (int rr = 0; rr < 4; ++rr) {
            const long long row = row0 + wrow + i * 16 + hi * 4 + rr;
            const float bb = bv[row];
#pragma unroll
            for (int j = 0; j < 4; ++j) {
                const long long col = col0 + wcol + j * 16 + lr;
                vtb[row * 8192 + col] = f2bf(acc[i][j][rr] + bb);
            }
        }
}

// P = exp(Q @ K^T) + fused row-sum atomics. Grid (8,8,4) = 256 blocks, BM=256.
__global__ __launch_bounds__(512, 2) void gemm_exp8(
    const uint16_t* __restrict__ Q, const uint16_t* __restrict__ Km,
    uint16_t* __restrict__ P, float* __restrict__ sums)
{
    __shared__ __attribute__((aligned(16))) uint16_t lds[2 * 512 * 64];
    const int z = blockIdx.z;
    const long long row0 = (long long)blockIdx.x * 256;
    const long long col0 = (long long)blockIdx.y * 256;
    const uint16_t* Ab = Q  + (long long)z * 2048 * 1024 + row0 * 1024;
    const uint16_t* Bb = Km + (long long)z * 2048 * 1024 + col0 * 1024;
    uint16_t* Cb = P + (long long)z * 2048 * 2048;
    float* ax = sums + (long long)z * 2048;

    f32x4 acc[8][4] = {};
    gemm8<8>(lds, Ab, 1024, Bb, 1024, 16, acc);

    const int tid = threadIdx.x;
    const int wave = tid >> 6, lane = tid & 63;
    const int lr = lane & 15, hi = lane >> 4;
    const int wrow = (wave >> 2) * 128, wcol = (wave & 3) * 64;
#pragma unroll
    for (int i = 0; i < 8; ++i)
#pragma unroll
        for (int rr = 0; rr < 4; ++rr) {
            const long long row = row0 + wrow + i * 16 + hi * 4 + rr;
            float s = 0.f;
#pragma unroll
            for (int j = 0; j < 4; ++j) {
                const long long col = col0 + wcol + j * 16 + lr;
                const float v = __expf(acc[i][j][rr]);
                Cb[row * 2048 + col] = f2bf(v);
                s += v;
            }
            s += __shfl_xor(s, 1);
            s += __shfl_xor(s, 2);
            s += __shfl_xor(s, 4);
            s += __shfl_xor(s, 8);
            if (lr == 0) atomicAdd(&ax[row], s);
        }
}

// out = (P @ V) * rcp(sums[row]). Grid (16,4,4) = 256 blocks, BM=128, NT=32.
__global__ __launch_bounds__(512, 2) void gemm_pv8(
    const uint16_t* __restrict__ P, const uint16_t* __restrict__ Vt,
    float* __restrict__ Out, const float* __restrict__ sums)
{
    __shared__ __attribute__((aligned(16))) uint16_t lds[2 * 384 * 64];
    const int z = blockIdx.z;
    const long long row0 = (long long)blockIdx.x * 128;   // token row
    const long long col0 = (long long)blockIdx.y * 256;   // D col
    const uint16_t* Ab = P + (long long)z * 2048 * 2048 + row0 * 2048;
    const uint16_t* Bb = Vt + col0 * 8192 + (long long)z * 2048;
    float* Cb = Out + (long long)z * 2048 * 1024;
    const float* ax = sums + (long long)z * 2048;

    f32x4 acc[4][4] = {};
    gemm8<4>(lds, Ab, 2048, Bb, 8192, 32, acc);

    const int tid = threadIdx.x;
    const int wave = tid >> 6, lane = tid & 63;
    const int lr = lane & 15, hi = lane >> 4;
    const int wrow = (wave >> 2) * 64, wcol = (wave & 3) * 64;
#pragma unroll
    for (int i = 0; i < 4; ++i)
#pragma unroll
        for (int rr = 0; rr < 4; ++rr) {
            const long long row = row0 + wrow + i * 16 + hi * 4 + rr;
            const float linv = __builtin_amdgcn_rcpf(ax[row]);
#pragma unroll
            for (int j = 0; j < 4; ++j) {
                const long long col = col0 + wcol + j * 16 + lr;
                Cb[row * 1024 + col] = acc[i][j][rr] * linv;
            }
        }
}

// One dispatch: cast x (blocks 0..8191), Wq/Wk/Wv (8192..11263), zero sums.
__global__ void cast_all(const float* __restrict__ x, const float* __restrict__ Wq,
                         const float* __restrict__ Wk, const float* __restrict__ Wv,
                         uint16_t* __restrict__ xb, uint16_t* __restrict__ wqb,
                         uint16_t* __restrict__ wkb, uint16_t* __restrict__ wvb,
                         float* __restrict__ sums) {
    const int b = blockIdx.x;
    const float* in;
    uint16_t* out;
    int i;
    if (b < 8192)       { in = x;  out = xb;  i = b * 256 + threadIdx.x; }
    else if (b < 9216)  { in = Wq; out = wqb; i = (b - 8192) * 256 + threadIdx.x; }
    else if (b < 10240) { in = Wk; out = wkb; i = (b - 9216) * 256 + threadIdx.x; }
    else if (b < 11264) { in = Wv; out = wvb; i = (b - 10240) * 256 + threadIdx.x; }
    else {
        int j = (b - 11264) * 256 + threadIdx.x;   // 8 blocks x 256 x float4 = 8192
        ((float4*)sums)[j] = make_float4(0.f, 0.f, 0.f, 0.f);
        return;
    }
    float4 v = ((const float4*)in)[i];
    ushort4 o = make_ushort4(f2bf(v.x), f2bf(v.y), f2bf(v.z), f2bf(v.w));
    ((ushort4*)out)[i] = o;
}

extern "C" void kernel_launch(void* const* d_in, const int* in_sizes, int n_in,
                              void* d_out, int out_size, void* d_ws, size_t ws_size,
                              hipStream_t stream) {
    const float* x  = (const float*)d_in[0];
    const float* Wq = (const float*)d_in[1];
    const float* bq = (const float*)d_in[2];
    const float* Wk = (const float*)d_in[3];
    const float* bk = (const float*)d_in[4];
    const float* Wv = (const float*)d_in[5];
    const float* bv = (const float*)d_in[6];

    // workspace carve (~102 MiB)
    uint8_t* w = (uint8_t*)d_ws;
    uint16_t* xb  = (uint16_t*)w; w += (size_t)8192 * 1024 * 2;
    uint16_t* wqb = (uint16_t*)w; w += (size_t)1024 * 1024 * 2;
    uint16_t* wkb = (uint16_t*)w; w += (size_t)1024 * 1024 * 2;
    uint16_t* wvb = (uint16_t*)w; w += (size_t)1024 * 1024 * 2;
    uint16_t* qb  = (uint16_t*)w; w += (size_t)8192 * 1024 * 2;
    uint16_t* kb  = (uint16_t*)w; w += (size_t)8192 * 1024 * 2;
    uint16_t* vtb = (uint16_t*)w; w += (size_t)8192 * 1024 * 2;   // [1024][8192]
    uint16_t* pb  = (uint16_t*)w; w += (size_t)4 * 2048 * 2048 * 2;
    float*    sums = (float*)w;  w += (size_t)8192 * 4;

    // casts + zero the exp-sum accumulator (1 dispatch)
    cast_all<<<dim3(11272), dim3(256), 0, stream>>>(x, Wq, Wk, Wv,
                                                    xb, wqb, wkb, wvb, sums);
    // Q (pre-scaled 2^-5) & K: 8-phase 256x256, 256 blocks
    qk_proj8<<<dim3(32, 8), dim3(512), 0, stream>>>(xb, wqb, wkb, bq, bk, qb, kb);
    // V^T: 8-phase 128x256, 256 blocks
    vt_proj8<<<dim3(8, 32), dim3(512), 0, stream>>>(xb, wvb, bv, vtb);
    // P = exp(Q @ K^T) + fused row sums: 8-phase 256x256, 256 blocks
    gemm_exp8<<<dim3(8, 8, 4), dim3(512), 0, stream>>>(qb, kb, pb, sums);
    // out = (P @ V) * rcp(sums): 8-phase 128x256, 256 blocks
    gemm_pv8<<<dim3(16, 4, 4), dim3(512), 0, stream>>>(pb, vtb, (float*)d_out, sums);
}

// Round 5
// 233.260 us; speedup vs baseline: 1.0250x; 1.0250x over previous
//
#include <hip/hip_runtime.h>
#include <stdint.h>

// Self-attention, B=4, S=2048, D=1024, fp32 in/out, bf16 MFMA internally.
// R10: R8 (best, 224.9us) + XCD-local job ordering for exp/pv.
//   Diagnosis: exp/pv are HBM-bound (exp: 111 MB @ 2.4 TB/s = its 47us),
//   with 2.3x fetch overfetch from cross-XCD panel scatter. The m97 cores
//   are kept verbatim (proj measured 931 TF = structure ceiling).
//   Change: decode job ids so each XCD's contiguous id slice is one
//   batch-half traversed row-major (panel working set <= 4MB L2):
//     exp: XCD slice = {z, 8 cols}x{16 rows}: K-set 2MB resident, Q x8 reuse
//     pv:  XCD slice = {z, 8 rows}x{8 cols}: Vt-set 4MB, P-panel x8 reuse

typedef float f32x4 __attribute__((ext_vector_type(4)));
typedef short s16x8 __attribute__((ext_vector_type(8)));

__device__ __forceinline__ uint16_t f2bf(float f) {
    uint32_t u = __float_as_uint(f);
    u += 0x7fffu + ((u >> 16) & 1u);   // round-to-nearest-even
    return (uint16_t)(u >> 16);
}

#define GLOAD16(gp, lp)                                                  \
    __builtin_amdgcn_global_load_lds(                                    \
        (const __attribute__((address_space(1))) uint32_t*)(gp),         \
        (__attribute__((address_space(3))) uint32_t*)(lp), 16, 0, 0)

// bijective XCD-contiguity swizzle; valid because every grid here is %8==0.
// Hardware round-robins blockIdx across XCDs (b%8); this makes XCD x own
// the contiguous id range [x*nwg/8, (x+1)*nwg/8) in temporal order.
__device__ __forceinline__ int xcd_swz(int b, int nwg) {
    return (b & 7) * (nwg >> 3) + (b >> 3);
}

// ---------------------------------------------------------------------------
// BK=64 swizzle (verified SQ_LDS_BANK_CONFLICT=0): LDS chunk cs (16B units)
// holds global kchunk (cs&7)^((cs>>3)&7) of row cs>>3. Fragment read for
// (row, kc): row*64 + (kc^(row&7))*8. C/D: row=(lane>>4)*4+reg, col=lane&15.
// 2-barrier K-loop, 128x128 tile, 4 waves (2x2 of 64x64), acc[4][4].
// ---------------------------------------------------------------------------
__device__ __forceinline__ void gemm_core(
    uint16_t* __restrict__ As, uint16_t* __restrict__ Bs,
    const uint16_t* __restrict__ Ag, const long long lda,
    const uint16_t* __restrict__ Bg, const long long ldb,
    const int NT, f32x4 (&acc)[4][4])
{
    const int t = threadIdx.x;
    const int wave = t >> 6, lane = t & 63;
    const int wm = (wave >> 1) * 64, wn = (wave & 1) * 64;
    const int lr = lane & 15, hi = lane >> 4, lr7 = lane & 7;

    const uint16_t* gA[4]; const uint16_t* gB[4];
    uint16_t* lA[4]; uint16_t* lB[4];
#pragma unroll
    for (int p = 0; p < 4; ++p) {
        const int cs = p * 256 + t;
        const int rr = cs >> 3;
        const int kc = ((cs & 7) ^ (rr & 7)) * 8;
        gA[p] = Ag + (long long)rr * lda + kc;
        gB[p] = Bg + (long long)rr * ldb + kc;
        lA[p] = As + (p * 256 + wave * 64) * 8;
        lB[p] = Bs + (p * 256 + wave * 64) * 8;
    }

    for (int k0 = 0; k0 < NT * 64; k0 += 64) {
#pragma unroll
        for (int p = 0; p < 4; ++p) GLOAD16(gA[p] + k0, lA[p]);
#pragma unroll
        for (int p = 0; p < 4; ++p) GLOAD16(gB[p] + k0, lB[p]);
        __syncthreads();
#pragma unroll
        for (int kk = 0; kk < 2; ++kk) {
            const int lka = ((kk * 4 + hi) ^ lr7) * 8;
            s16x8 a[4], b[4];
#pragma unroll
            for (int i = 0; i < 4; ++i)
                a[i] = *(const s16x8*)(As + (wm + i * 16 + lr) * 64 + lka);
#pragma unroll
            for (int j = 0; j < 4; ++j)
                b[j] = *(const s16x8*)(Bs + (wn + j * 16 + lr) * 64 + lka);
#pragma unroll
            for (int i = 0; i < 4; ++i)
#pragma unroll
                for (int j = 0; j < 4; ++j)
                    acc[i][j] = __builtin_amdgcn_mfma_f32_16x16x32_bf16(
                        a[i], b[j], acc[i][j], 0, 0, 0);
        }
        __syncthreads();
    }
}

// Projections, one dispatch, 1536 blocks (XCD-swizzled):
//   id < 1024: Q/K. mat=id>>9 (0=Q,1=K); rowblk=(id>>3)&63; colblk=id&7.
//              out = (x_tile @ W_tile^T + b) [*2^-5 for Q]
//   id >= 1024: V^T. vid=id-1024; rb=vid&7 (Vt rows); cb=vid>>3 (tokens).
//              Vt_tile = Wv_tile @ x_tile^T + bv(row)
// XCD slice (192 ids): x-row-panel reused 8x consecutively; W-set ~2MB
// resident -> already L2-friendly (measured 931 TF). Unchanged from R8.
__global__ __launch_bounds__(256, 3) void proj_all(
    const uint16_t* __restrict__ xb, const uint16_t* __restrict__ wqb,
    const uint16_t* __restrict__ wkb, const uint16_t* __restrict__ wvb,
    const float* __restrict__ bq, const float* __restrict__ bk,
    const float* __restrict__ bv,
    uint16_t* __restrict__ qb, uint16_t* __restrict__ kb,
    uint16_t* __restrict__ vtb)
{
    __shared__ __attribute__((aligned(16))) uint16_t As[128 * 64];
    __shared__ __attribute__((aligned(16))) uint16_t Bs[128 * 64];

    const int id = xcd_swz(blockIdx.x, 1536);
    const int t = threadIdx.x;
    const int wave = t >> 6, lane = t & 63;
    const int wm = (wave >> 1) * 64, wn = (wave & 1) * 64;
    const int lr = lane & 15, hi = lane >> 4;

    f32x4 acc[4][4] = {};

    if (id < 1024) {
        const int mat = id >> 9;
        const long long row0 = (long long)((id >> 3) & 63) * 128;
        const long long col0 = (long long)(id & 7) * 128;
        const uint16_t* W = mat ? wkb : wqb;
        gemm_core(As, Bs, xb + row0 * 1024, 1024, W + col0 * 1024, 1024, 16, acc);

        const float* bias = mat ? bk : bq;
        uint16_t* out = mat ? kb : qb;
        const float scale = mat ? 1.0f : 0.03125f;
#pragma unroll
        for (int i = 0; i < 4; ++i)
#pragma unroll
            for (int rr = 0; rr < 4; ++rr) {
                const long long row = row0 + wm + i * 16 + hi * 4 + rr;
#pragma unroll
                for (int j = 0; j < 4; ++j) {
                    const long long col = col0 + wn + j * 16 + lr;
                    out[row * 1024 + col] = f2bf((acc[i][j][rr] + bias[col]) * scale);
                }
            }
    } else {
        const int vid = id - 1024;
        const long long row0 = (long long)(vid & 7) * 128;    // Vt row
        const long long col0 = (long long)(vid >> 3) * 128;   // token col
        gemm_core(As, Bs, wvb + row0 * 1024, 1024, xb + col0 * 1024, 1024, 16, acc);
#pragma unroll
        for (int i = 0; i < 4; ++i)
#pragma unroll
            for (int rr = 0; rr < 4; ++rr) {
                const long long row = row0 + wm + i * 16 + hi * 4 + rr;
                const float bb = bv[row];
#pragma unroll
                for (int j = 0; j < 4; ++j) {
                    const long long col = col0 + wn + j * 16 + lr;
                    vtb[row * 8192 + col] = f2bf(acc[i][j][rr] + bb);
                }
            }
    }
}

// P = exp(Q @ K^T) + fused row-sum atomics. 1024 blocks, 128x128 tiles.
// XCD-local decode: XCD slice (128 ids) = batch z=(id>>8), col-half
// ((id>>7)&1), rows 0..15 row-major. Per-XCD working set: K half-set 2MB
// resident in L2 (fetched once); Q panel reused 8x back-to-back.
__global__ __launch_bounds__(256, 3) void gemm_exp(
    const uint16_t* __restrict__ Q, const uint16_t* __restrict__ Km,
    uint16_t* __restrict__ P, float* __restrict__ sums)
{
    __shared__ __attribute__((aligned(16))) uint16_t As[128 * 64];
    __shared__ __attribute__((aligned(16))) uint16_t Bs[128 * 64];

    const int id = xcd_swz(blockIdx.x, 1024);
    const int z = id >> 8;
    const long long row0 = (long long)((id >> 3) & 15) * 128;
    const long long col0 = (long long)(((id >> 7) & 1) * 8 + (id & 7)) * 128;

    const uint16_t* Ab = Q  + (long long)z * 2048 * 1024 + row0 * 1024;
    const uint16_t* Bb = Km + (long long)z * 2048 * 1024 + col0 * 1024;
    uint16_t* Cb = P + (long long)z * 2048 * 2048;
    float* ax = sums + (long long)z * 2048;

    f32x4 acc[4][4] = {};
    gemm_core(As, Bs, Ab, 1024, Bb, 1024, 16, acc);

    const int t = threadIdx.x;
    const int wave = t >> 6, lane = t & 63;
    const int wm = (wave >> 1) * 64, wn = (wave & 1) * 64;
    const int lr = lane & 15, hi = lane >> 4;
#pragma unroll
    for (int i = 0; i < 4; ++i)
#pragma unroll
        for (int rr = 0; rr < 4; ++rr) {
            const long long row = row0 + wm + i * 16 + hi * 4 + rr;
            float s = 0.f;
#pragma unroll
            for (int j = 0; j < 4; ++j) {
                const long long col = col0 + wn + j * 16 + lr;
                const float v = __expf(acc[i][j][rr]);
                Cb[row * 2048 + col] = f2bf(v);
                s += v;
            }
            s += __shfl_xor(s, 1);
            s += __shfl_xor(s, 2);
            s += __shfl_xor(s, 4);
            s += __shfl_xor(s, 8);
            if (lr == 0) atomicAdd(&ax[row], s);
        }
}

// out = (P @ V) * rcp(sums[row]). 512 blocks, 128x128 tiles, NT=32.
// XCD-local decode: XCD slice (64 ids) = batch z=(id>>7), row-half
// ((id>>6)&1), cols 0..7 row-major. Per-XCD: Vt half-set 4MB in L2,
// P row-panel (512KB) reused 8x back-to-back.
__global__ __launch_bounds__(256, 3) void gemm_pv(
    const uint16_t* __restrict__ P, const uint16_t* __restrict__ Vt,
    float* __restrict__ Out, const float* __restrict__ sums)
{
    __shared__ __attribute__((aligned(16))) uint16_t As[128 * 64];
    __shared__ __attribute__((aligned(16))) uint16_t Bs[128 * 64];

    const int id = xcd_swz(blockIdx.x, 512);
    const int z = id >> 7;
    const long long row0 = (long long)(((id >> 6) & 1) * 8 + ((id >> 3) & 7)) * 128;
    const long long col0 = (long long)(id & 7) * 128;

    const uint16_t* Ab = P + (long long)z * 2048 * 2048 + row0 * 2048;
    const uint16_t* Bb = Vt + col0 * 8192 + (long long)z * 2048;
    float* Cb = Out + (long long)z * 2048 * 1024;
    const float* ax = sums + (long long)z * 2048;

    f32x4 acc[4][4] = {};
    gemm_core(As, Bs, Ab, 2048, Bb, 8192, 32, acc);

    const int t = threadIdx.x;
    const int wave = t >> 6, lane = t & 63;
    const int wm = (wave >> 1) * 64, wn = (wave & 1) * 64;
    const int lr = lane & 15, hi = lane >> 4;
#pragma unroll
    for (int i = 0; i < 4; ++i)
#pragma unroll
        for (int rr = 0; rr < 4; ++rr) {
            const long long row = row0 + wm + i * 16 + hi * 4 + rr;
            const float linv = __builtin_amdgcn_rcpf(ax[row]);
#pragma unroll
            for (int j = 0; j < 4; ++j) {
                const long long col = col0 + wn + j * 16 + lr;
                Cb[row * 1024 + col] = acc[i][j][rr] * linv;
            }
        }
}

// One dispatch: cast x (blocks 0..8191), Wq/Wk/Wv (8192..11263), zero sums.
__global__ void cast_all(const float* __restrict__ x, const float* __restrict__ Wq,
                         const float* __restrict__ Wk, const float* __restrict__ Wv,
                         uint16_t* __restrict__ xb, uint16_t* __restrict__ wqb,
                         uint16_t* __restrict__ wkb, uint16_t* __restrict__ wvb,
                         float* __restrict__ sums) {
    const int b = blockIdx.x;
    const float* in;
    uint16_t* out;
    int i;
    if (b < 8192)       { in = x;  out = xb;  i = b * 256 + threadIdx.x; }
    else if (b < 9216)  { in = Wq; out = wqb; i = (b - 8192) * 256 + threadIdx.x; }
    else if (b < 10240) { in = Wk; out = wkb; i = (b - 9216) * 256 + threadIdx.x; }
    else if (b < 11264) { in = Wv; out = wvb; i = (b - 10240) * 256 + threadIdx.x; }
    else {
        int j = (b - 11264) * 256 + threadIdx.x;   // 8 blocks x 256 x float4 = 8192
        ((float4*)sums)[j] = make_float4(0.f, 0.f, 0.f, 0.f);
        return;
    }
    float4 v = ((const float4*)in)[i];
    ushort4 o = make_ushort4(f2bf(v.x), f2bf(v.y), f2bf(v.z), f2bf(v.w));
    ((ushort4*)out)[i] = o;
}

extern "C" void kernel_launch(void* const* d_in, const int* in_sizes, int n_in,
                              void* d_out, int out_size, void* d_ws, size_t ws_size,
                              hipStream_t stream) {
    const float* x  = (const float*)d_in[0];
    const float* Wq = (const float*)d_in[1];
    const float* bq = (const float*)d_in[2];
    const float* Wk = (const float*)d_in[3];
    const float* bk = (const float*)d_in[4];
    const float* Wv = (const float*)d_in[5];
    const float* bv = (const float*)d_in[6];

    // workspace carve (~102 MiB)
    uint8_t* w = (uint8_t*)d_ws;
    uint16_t* xb  = (uint16_t*)w; w += (size_t)8192 * 1024 * 2;
    uint16_t* wqb = (uint16_t*)w; w += (size_t)1024 * 1024 * 2;
    uint16_t* wkb = (uint16_t*)w; w += (size_t)1024 * 1024 * 2;
    uint16_t* wvb = (uint16_t*)w; w += (size_t)1024 * 1024 * 2;
    uint16_t* qb  = (uint16_t*)w; w += (size_t)8192 * 1024 * 2;
    uint16_t* kb  = (uint16_t*)w; w += (size_t)8192 * 1024 * 2;
    uint16_t* vtb = (uint16_t*)w; w += (size_t)8192 * 1024 * 2;   // [1024][8192]
    uint16_t* pb  = (uint16_t*)w; w += (size_t)4 * 2048 * 2048 * 2;
    float*    sums = (float*)w;  w += (size_t)8192 * 4;

    // casts + zero the exp-sum accumulator (1 dispatch)
    cast_all<<<dim3(11272), dim3(256), 0, stream>>>(x, Wq, Wk, Wv,
                                                    xb, wqb, wkb, wvb, sums);
    // Q (pre-scaled 2^-5), K, V^T: unpaired 128x128, 1536 blocks, 3/CU
    proj_all<<<dim3(1536), dim3(256), 0, stream>>>(xb, wqb, wkb, wvb,
                                                   bq, bk, bv, qb, kb, vtb);
    // P = exp(Q @ K^T) + fused row sums: 128x128, 1024 blocks, XCD-local
    gemm_exp<<<dim3(1024), dim3(256), 0, stream>>>(qb, kb, pb, sums);
    // out = (P @ V) * rcp(sums): 128x128, 512 blocks, XCD-local
    gemm_pv<<<dim3(512), dim3(256), 0, stream>>>(pb, vtb, (float*)d_out, sums);
}

// Round 6
// 221.213 us; speedup vs baseline: 1.0808x; 1.0545x over previous
//
#include <hip/hip_runtime.h>
#include <stdint.h>

// Self-attention, B=4, S=2048, D=1024, fp32 in/out, bf16 MFMA internally.
// R11: R8 (best, 224.9us; R10's XCD-local exp/pv decodes reverted -- measured
//      -8.4us harm) + register diet to reach 4 blocks/CU:
//      - gA/gB pointer arrays (8 ptr pairs = 32 VGPR) -> 1 base + 4 u32
//        self-advancing byte offsets per matrix (8 VGPR total)
//      - lA/lB pointer arrays -> compile-time LDS offsets + wave*512
//      - __launch_bounds__(256,4): total regs ~(50 arch + 64 acc) <= 128
//        -> 4 waves/SIMD -> 4 blocks/CU (was 140 regs -> 3/CU).
//      Mechanism: the m97 2-barrier core stalls ~20% in the all-waves
//      vmcnt(0)+barrier drain; a 4th co-resident block fills that window.

typedef float f32x4 __attribute__((ext_vector_type(4)));
typedef short s16x8 __attribute__((ext_vector_type(8)));

__device__ __forceinline__ uint16_t f2bf(float f) {
    uint32_t u = __float_as_uint(f);
    u += 0x7fffu + ((u >> 16) & 1u);   // round-to-nearest-even
    return (uint16_t)(u >> 16);
}

#define GLOAD16(gp, lp)                                                  \
    __builtin_amdgcn_global_load_lds(                                    \
        (const __attribute__((address_space(1))) uint32_t*)(gp),         \
        (__attribute__((address_space(3))) uint32_t*)(lp), 16, 0, 0)

// bijective XCD-contiguity swizzle; valid because every grid here is %8==0.
__device__ __forceinline__ int xcd_swz(int b, int nwg) {
    return (b & 7) * (nwg >> 3) + (b >> 3);
}

// ---------------------------------------------------------------------------
// BK=64 swizzle (verified SQ_LDS_BANK_CONFLICT=0): LDS chunk cs (16B units)
// holds global kchunk (cs&7)^((cs>>3)&7) of row cs>>3. Fragment read for
// (row, kc): row*64 + (kc^(row&7))*8. C/D: row=(lane>>4)*4+reg, col=lane&15.
// 2-barrier K-loop, 128x128 tile, 4 waves (2x2 of 64x64), acc[4][4].
// Staging addresses kept as u32 byte offsets (self-advancing +128B/K-step)
// off one 64-bit base per matrix to hold arch-VGPR count down (4-blocks/CU).
// ---------------------------------------------------------------------------
__device__ __forceinline__ void gemm_core(
    uint16_t* __restrict__ As, uint16_t* __restrict__ Bs,
    const uint16_t* __restrict__ Ag, const int lda,
    const uint16_t* __restrict__ Bg, const int ldb,
    const int NT, f32x4 (&acc)[4][4])
{
    const int t = threadIdx.x;
    const int wave = t >> 6, lane = t & 63;
    const int wm = (wave >> 1) * 64, wn = (wave & 1) * 64;
    const int lr = lane & 15, hi = lane >> 4, lr7 = lane & 7;

    uint32_t offA[4], offB[4];          // byte offsets into Ag/Bg
#pragma unroll
    for (int p = 0; p < 4; ++p) {
        const int cs = p * 256 + t;
        const int rr = cs >> 3;
        const int kc = ((cs & 7) ^ (rr & 7)) * 8;
        offA[p] = (uint32_t)((rr * lda + kc) * 2);
        offB[p] = (uint32_t)((rr * ldb + kc) * 2);
    }
    const int lws = wave * 512;         // LDS write base (uint16 units)

    for (int it = 0; it < NT; ++it) {
#pragma unroll
        for (int p = 0; p < 4; ++p) {
            GLOAD16((const uint8_t*)Ag + offA[p], As + p * 2048 + lws);
            offA[p] += 128;
        }
#pragma unroll
        for (int p = 0; p < 4; ++p) {
            GLOAD16((const uint8_t*)Bg + offB[p], Bs + p * 2048 + lws);
            offB[p] += 128;
        }
        __syncthreads();
#pragma unroll
        for (int kk = 0; kk < 2; ++kk) {
            const int lka = ((kk * 4 + hi) ^ lr7) * 8;
            s16x8 a[4], b[4];
#pragma unroll
            for (int i = 0; i < 4; ++i)
                a[i] = *(const s16x8*)(As + (wm + i * 16 + lr) * 64 + lka);
#pragma unroll
            for (int j = 0; j < 4; ++j)
                b[j] = *(const s16x8*)(Bs + (wn + j * 16 + lr) * 64 + lka);
#pragma unroll
            for (int i = 0; i < 4; ++i)
#pragma unroll
                for (int j = 0; j < 4; ++j)
                    acc[i][j] = __builtin_amdgcn_mfma_f32_16x16x32_bf16(
                        a[i], b[j], acc[i][j], 0, 0, 0);
        }
        __syncthreads();
    }
}

// Projections, one dispatch, 1536 blocks (XCD-swizzled):
//   id < 1024: Q/K. mat=id>>9 (0=Q,1=K); rowblk=(id>>3)&63; colblk=id&7.
//              out = (x_tile @ W_tile^T + b) [*2^-5 for Q]
//   id >= 1024: V^T. vid=id-1024; rb=vid&7 (Vt rows); cb=vid>>3 (tokens).
//              Vt_tile = Wv_tile @ x_tile^T + bv(row)
__global__ __launch_bounds__(256, 4) void proj_all(
    const uint16_t* __restrict__ xb, const uint16_t* __restrict__ wqb,
    const uint16_t* __restrict__ wkb, const uint16_t* __restrict__ wvb,
    const float* __restrict__ bq, const float* __restrict__ bk,
    const float* __restrict__ bv,
    uint16_t* __restrict__ qb, uint16_t* __restrict__ kb,
    uint16_t* __restrict__ vtb)
{
    __shared__ __attribute__((aligned(16))) uint16_t As[128 * 64];
    __shared__ __attribute__((aligned(16))) uint16_t Bs[128 * 64];

    const int id = xcd_swz(blockIdx.x, 1536);
    const int t = threadIdx.x;
    const int wave = t >> 6, lane = t & 63;
    const int wm = (wave >> 1) * 64, wn = (wave & 1) * 64;
    const int lr = lane & 15, hi = lane >> 4;

    f32x4 acc[4][4] = {};

    if (id < 1024) {
        const int mat = id >> 9;
        const long long row0 = (long long)((id >> 3) & 63) * 128;
        const long long col0 = (long long)(id & 7) * 128;
        const uint16_t* W = mat ? wkb : wqb;
        gemm_core(As, Bs, xb + row0 * 1024, 1024, W + col0 * 1024, 1024, 16, acc);

        const float* bias = mat ? bk : bq;
        uint16_t* out = mat ? kb : qb;
        const float scale = mat ? 1.0f : 0.03125f;
#pragma unroll
        for (int i = 0; i < 4; ++i)
#pragma unroll
            for (int rr = 0; rr < 4; ++rr) {
                const long long row = row0 + wm + i * 16 + hi * 4 + rr;
#pragma unroll
                for (int j = 0; j < 4; ++j) {
                    const long long col = col0 + wn + j * 16 + lr;
                    out[row * 1024 + col] = f2bf((acc[i][j][rr] + bias[col]) * scale);
                }
            }
    } else {
        const int vid = id - 1024;
        const long long row0 = (long long)(vid & 7) * 128;    // Vt row
        const long long col0 = (long long)(vid >> 3) * 128;   // token col
        gemm_core(As, Bs, wvb + row0 * 1024, 1024, xb + col0 * 1024, 1024, 16, acc);
#pragma unroll
        for (int i = 0; i < 4; ++i)
#pragma unroll
            for (int rr = 0; rr < 4; ++rr) {
                const long long row = row0 + wm + i * 16 + hi * 4 + rr;
                const float bb = bv[row];
#pragma unroll
                for (int j = 0; j < 4; ++j) {
                    const long long col = col0 + wn + j * 16 + lr;
                    vtb[row * 8192 + col] = f2bf(acc[i][j][rr] + bb);
                }
            }
    }
}

// P = exp(Q @ K^T) + fused row-sum atomics. 1024 blocks, 128x128 tiles.
// R8 decode (R10's XCD-local variant measured slower; reverted).
__global__ __launch_bounds__(256, 4) void gemm_exp(
    const uint16_t* __restrict__ Q, const uint16_t* __restrict__ Km,
    uint16_t* __restrict__ P, float* __restrict__ sums)
{
    __shared__ __attribute__((aligned(16))) uint16_t As[128 * 64];
    __shared__ __attribute__((aligned(16))) uint16_t Bs[128 * 64];

    const int id = xcd_swz(blockIdx.x, 1024);
    const int z = id >> 8;
    const int rem = id & 255;
    const long long row0 = (long long)(rem & 15) * 128;
    const long long col0 = (long long)(rem >> 4) * 128;

    const uint16_t* Ab = Q  + (long long)z * 2048 * 1024 + row0 * 1024;
    const uint16_t* Bb = Km + (long long)z * 2048 * 1024 + col0 * 1024;
    uint16_t* Cb = P + (long long)z * 2048 * 2048;
    float* ax = sums + (long long)z * 2048;

    f32x4 acc[4][4] = {};
    gemm_core(As, Bs, Ab, 1024, Bb, 1024, 16, acc);

    const int t = threadIdx.x;
    const int wave = t >> 6, lane = t & 63;
    const int wm = (wave >> 1) * 64, wn = (wave & 1) * 64;
    const int lr = lane & 15, hi = lane >> 4;
#pragma unroll
    for (int i = 0; i < 4; ++i)
#pragma unroll
        for (int rr = 0; rr < 4; ++rr) {
            const long long row = row0 + wm + i * 16 + hi * 4 + rr;
            float s = 0.f;
#pragma unroll
            for (int j = 0; j < 4; ++j) {
                const long long col = col0 + wn + j * 16 + lr;
                const float v = __expf(acc[i][j][rr]);
                Cb[row * 2048 + col] = f2bf(v);
                s += v;
            }
            s += __shfl_xor(s, 1);
            s += __shfl_xor(s, 2);
            s += __shfl_xor(s, 4);
            s += __shfl_xor(s, 8);
            if (lr == 0) atomicAdd(&ax[row], s);
        }
}

// out = (P @ V) * rcp(sums[row]). 512 blocks, 128x128 tiles, NT=32.
// R8 decode (reverted from R10).
__global__ __launch_bounds__(256, 4) void gemm_pv(
    const uint16_t* __restrict__ P, const uint16_t* __restrict__ Vt,
    float* __restrict__ Out, const float* __restrict__ sums)
{
    __shared__ __attribute__((aligned(16))) uint16_t As[128 * 64];
    __shared__ __attribute__((aligned(16))) uint16_t Bs[128 * 64];

    const int id = xcd_swz(blockIdx.x, 512);
    const int z = id >> 7;
    const int rem = id & 127;
    const long long row0 = (long long)(rem & 15) * 128;   // token row
    const long long col0 = (long long)(rem >> 4) * 128;   // D col

    const uint16_t* Ab = P + (long long)z * 2048 * 2048 + row0 * 2048;
    const uint16_t* Bb = Vt + col0 * 8192 + (long long)z * 2048;
    float* Cb = Out + (long long)z * 2048 * 1024;
    const float* ax = sums + (long long)z * 2048;

    f32x4 acc[4][4] = {};
    gemm_core(As, Bs, Ab, 2048, Bb, 8192, 32, acc);

    const int t = threadIdx.x;
    const int wave = t >> 6, lane = t & 63;
    const int wm = (wave >> 1) * 64, wn = (wave & 1) * 64;
    const int lr = lane & 15, hi = lane >> 4;
#pragma unroll
    for (int i = 0; i < 4; ++i)
#pragma unroll
        for (int rr = 0; rr < 4; ++rr) {
            const long long row = row0 + wm + i * 16 + hi * 4 + rr;
            const float linv = __builtin_amdgcn_rcpf(ax[row]);
#pragma unroll
            for (int j = 0; j < 4; ++j) {
                const long long col = col0 + wn + j * 16 + lr;
                Cb[row * 1024 + col] = acc[i][j][rr] * linv;
            }
        }
}

// One dispatch: cast x (blocks 0..8191), Wq/Wk/Wv (8192..11263), zero sums.
__global__ void cast_all(const float* __restrict__ x, const float* __restrict__ Wq,
                         const float* __restrict__ Wk, const float* __restrict__ Wv,
                         uint16_t* __restrict__ xb, uint16_t* __restrict__ wqb,
                         uint16_t* __restrict__ wkb, uint16_t* __restrict__ wvb,
                         float* __restrict__ sums) {
    const int b = blockIdx.x;
    const float* in;
    uint16_t* out;
    int i;
    if (b < 8192)       { in = x;  out = xb;  i = b * 256 + threadIdx.x; }
    else if (b < 9216)  { in = Wq; out = wqb; i = (b - 8192) * 256 + threadIdx.x; }
    else if (b < 10240) { in = Wk; out = wkb; i = (b - 9216) * 256 + threadIdx.x; }
    else if (b < 11264) { in = Wv; out = wvb; i = (b - 10240) * 256 + threadIdx.x; }
    else {
        int j = (b - 11264) * 256 + threadIdx.x;   // 8 blocks x 256 x float4 = 8192
        ((float4*)sums)[j] = make_float4(0.f, 0.f, 0.f, 0.f);
        return;
    }
    float4 v = ((const float4*)in)[i];
    ushort4 o = make_ushort4(f2bf(v.x), f2bf(v.y), f2bf(v.z), f2bf(v.w));
    ((ushort4*)out)[i] = o;
}

extern "C" void kernel_launch(void* const* d_in, const int* in_sizes, int n_in,
                              void* d_out, int out_size, void* d_ws, size_t ws_size,
                              hipStream_t stream) {
    const float* x  = (const float*)d_in[0];
    const float* Wq = (const float*)d_in[1];
    const float* bq = (const float*)d_in[2];
    const float* Wk = (const float*)d_in[3];
    const float* bk = (const float*)d_in[4];
    const float* Wv = (const float*)d_in[5];
    const float* bv = (const float*)d_in[6];

    // workspace carve (~102 MiB)
    uint8_t* w = (uint8_t*)d_ws;
    uint16_t* xb  = (uint16_t*)w; w += (size_t)8192 * 1024 * 2;
    uint16_t* wqb = (uint16_t*)w; w += (size_t)1024 * 1024 * 2;
    uint16_t* wkb = (uint16_t*)w; w += (size_t)1024 * 1024 * 2;
    uint16_t* wvb = (uint16_t*)w; w += (size_t)1024 * 1024 * 2;
    uint16_t* qb  = (uint16_t*)w; w += (size_t)8192 * 1024 * 2;
    uint16_t* kb  = (uint16_t*)w; w += (size_t)8192 * 1024 * 2;
    uint16_t* vtb = (uint16_t*)w; w += (size_t)8192 * 1024 * 2;   // [1024][8192]
    uint16_t* pb  = (uint16_t*)w; w += (size_t)4 * 2048 * 2048 * 2;
    float*    sums = (float*)w;  w += (size_t)8192 * 4;

    // casts + zero the exp-sum accumulator (1 dispatch)
    cast_all<<<dim3(11272), dim3(256), 0, stream>>>(x, Wq, Wk, Wv,
                                                    xb, wqb, wkb, wvb, sums);
    // Q (pre-scaled 2^-5), K, V^T: unpaired 128x128, 1536 blocks, 4/CU target
    proj_all<<<dim3(1536), dim3(256), 0, stream>>>(xb, wqb, wkb, wvb,
                                                   bq, bk, bv, qb, kb, vtb);
    // P = exp(Q @ K^T) + fused row sums: 128x128, 1024 blocks
    gemm_exp<<<dim3(1024), dim3(256), 0, stream>>>(qb, kb, pb, sums);
    // out = (P @ V) * rcp(sums): 128x128, 512 blocks
    gemm_pv<<<dim3(512), dim3(256), 0, stream>>>(pb, vtb, (float*)d_out, sums);
}